// Round 14
// baseline (344.278 us; speedup 1.0000x reference)
//
#include <hip/hip_runtime.h>
#include <hip/hip_bf16.h>
#include <math.h>

#define TT 2048
#define CC 1024
#define HH 16
#define DDIM 64
#define MM 8192
#define C3 3072
#define SBIAS 256.0f

typedef __bf16 bf16x8 __attribute__((ext_vector_type(8)));
typedef float f32x4 __attribute__((ext_vector_type(4)));

__device__ __forceinline__ float waveReduceSum(float v) {
#pragma unroll
  for (int off = 32; off > 0; off >>= 1) v += __shfl_xor(v, off, 64);
  return v;
}
__device__ __forceinline__ unsigned umn(unsigned a, unsigned b){ return a<b?a:b; }
__device__ __forceinline__ unsigned umed3(unsigned a, unsigned b, unsigned c){
  unsigned d;
  asm("v_med3_u32 %0, %1, %2, %3" : "=v"(d) : "v"(a), "v"(b), "v"(c));
  return d;
}

// async global->LDS, 16B per lane (linear dest, per-lane src carries swizzle)
__device__ __forceinline__ void gload16(const void* g, void* l) {
  __builtin_amdgcn_global_load_lds(
      (const __attribute__((address_space(1))) unsigned int*)g,
      (__attribute__((address_space(3))) unsigned int*)l, 16, 0, 0);
}

// ---------------- conversion bodies ----------------
__device__ __forceinline__ void conv_split_body(const float* __restrict__ src,
    __hip_bfloat16* __restrict__ hi, __hip_bfloat16* __restrict__ lo, size_t i)
{
  const float4* p = (const float4*)(src + i*8);
  float4 a = p[0], b = p[1];
  float v[8] = {a.x,a.y,a.z,a.w,b.x,b.y,b.z,b.w};
  bf16x8 H, L;
#pragma unroll
  for (int e = 0; e < 8; ++e) {
    __bf16 hb = (__bf16)v[e];
    H[e] = hb;
    L[e] = (__bf16)(v[e] - (float)hb);
  }
  *reinterpret_cast<bf16x8*>(hi + i*8) = H;
  *reinterpret_cast<bf16x8*>(lo + i*8) = L;
}

__device__ __forceinline__ void conv_bf16_body(const float* __restrict__ src,
    __hip_bfloat16* __restrict__ dst, size_t i)
{
  const float4* p = (const float4*)(src + i*8);
  float4 a = p[0], b = p[1];
  float v[8] = {a.x,a.y,a.z,a.w,b.x,b.y,b.z,b.w};
  bf16x8 H;
#pragma unroll
  for (int e = 0; e < 8; ++e) H[e] = (__bf16)v[e];
  *reinterpret_cast<bf16x8*>(dst + i*8) = H;
}

// mega1: conv_split(x) [0,1024) | conv_split(wat) [1024,2560)
__global__ __launch_bounds__(256) void mega1_k(
    const float* __restrict__ x, __hip_bfloat16* __restrict__ xhi, __hip_bfloat16* __restrict__ xlo,
    const float* __restrict__ wat, __hip_bfloat16* __restrict__ whi, __hip_bfloat16* __restrict__ wlo)
{
  int bid = blockIdx.x;
  if (bid < 1024) conv_split_body(x, xhi, xlo, (size_t)bid*256 + threadIdx.x);
  else            conv_split_body(wat, whi, wlo, (size_t)(bid-1024)*256 + threadIdx.x);
}

// mega2: mask [0,16) | conv_ks [16,2064) | conv_kb [2064,3088) | conv wpr [3088,3600)
__global__ __launch_bounds__(256) void mega2_k(
    const float* __restrict__ qkv, int* __restrict__ mask,
    const float* __restrict__ kst, __hip_bfloat16* __restrict__ ksb,
    float* __restrict__ ksn, float* __restrict__ ksnb,
    __hip_bfloat16* __restrict__ kb,
    const float* __restrict__ wpr, __hip_bfloat16* __restrict__ wprb)
{
  __shared__ float sm[64 + TT + 256];
  const int bid = blockIdx.x;
  const int tid = threadIdx.x;
  if (bid < 16) {
    const int h = bid;
    float* ql = sm;
    float* lg = sm + 64;
    float* red = sm + 64 + TT;
    if (tid < 64) ql[tid] = qkv[(size_t)(TT-1)*C3 + h*DDIM + tid];
    __syncthreads();
    float lmax = -INFINITY;
    for (int t = tid; t < TT; t += 256) {
      const float* kr = qkv + (size_t)t*C3 + CC + h*DDIM;
      float s = 0.f;
#pragma unroll
      for (int d = 0; d < 64; ++d) s += ql[d] * kr[d];
      s *= 0.125f;
      lg[t] = s;
      lmax = fmaxf(lmax, s);
    }
    red[tid] = lmax; __syncthreads();
    for (int off = 128; off > 0; off >>= 1) { if (tid < off) red[tid] = fmaxf(red[tid], red[tid+off]); __syncthreads(); }
    float mx = red[0];
    __syncthreads();
    float ls = 0.f;
    for (int t = tid; t < TT; t += 256) { float e = expf(lg[t]-mx); lg[t] = e; ls += e; }
    red[tid] = ls; __syncthreads();
    for (int off = 128; off > 0; off >>= 1) { if (tid < off) red[tid] += red[tid+off]; __syncthreads(); }
    float Z = red[0];
    for (int t = tid; t < TT; t += 256) mask[h*TT + t] = (lg[t]/Z >= 1.220703125e-4f) ? 1 : 0;
  } else if (bid < 2064) {
    int row = (bid - 16)*64 + (tid >> 2);
    int q = tid & 3;
    const float* src = kst + (size_t)row*64 + q*16;
    float s = 0.f;
    bf16x8 H0, H1;
#pragma unroll
    for (int i = 0; i < 2; ++i) {
      float4 a = ((const float4*)src)[i*2];
      float4 b = ((const float4*)src)[i*2+1];
      s += a.x*a.x + a.y*a.y + a.z*a.z + a.w*a.w
         + b.x*b.x + b.y*b.y + b.z*b.z + b.w*b.w;
      bf16x8 H;
      H[0]=(__bf16)a.x; H[1]=(__bf16)a.y; H[2]=(__bf16)a.z; H[3]=(__bf16)a.w;
      H[4]=(__bf16)b.x; H[5]=(__bf16)b.y; H[6]=(__bf16)b.z; H[7]=(__bf16)b.w;
      if (i == 0) H0 = H; else H1 = H;
    }
    s += __shfl_xor(s, 1, 64);
    s += __shfl_xor(s, 2, 64);
    *reinterpret_cast<bf16x8*>(ksb + (size_t)row*64 + q*16)     = H0;
    *reinterpret_cast<bf16x8*>(ksb + (size_t)row*64 + q*16 + 8) = H1;
    if (q == 0) { ksn[row] = s; ksnb[row] = s + SBIAS; }
  } else if (bid < 3088) {
    int e = (bid - 2064)*256 + tid;
    int dg = e & 7; int t = (e>>3) & (TT-1); int h = e >> 14;
    const float* src = qkv + (size_t)t*C3 + CC + h*64 + dg*8;
    __hip_bfloat16* dst = kb + ((size_t)(h*TT + t)*64 + dg*8);
#pragma unroll
    for (int i = 0; i < 8; ++i) dst[i] = __float2bfloat16(src[i]);
  } else {
    conv_bf16_body(wpr, wprb, (size_t)(bid - 3088)*256 + tid);
  }
}

// vnew [h*TT+t][dv] fp32 -> vbT [h][dv][t] bf16
__global__ __launch_bounds__(256) void vtrans_k(const float* __restrict__ vnew,
    __hip_bfloat16* __restrict__ vbT)
{
  __shared__ float tbuf[64][65];
  const int h = blockIdx.y, t0 = blockIdx.x*64, tid = threadIdx.x;
#pragma unroll
  for (int r = 0; r < 16; ++r) {
    int e = r*256 + tid; int row = e>>6, dv = e&63;
    tbuf[row][dv] = vnew[((size_t)h*TT + t0 + row)*64 + dv];
  }
  __syncthreads();
#pragma unroll
  for (int r = 0; r < 16; ++r) {
    int e = r*256 + tid; int dv = e>>6, tt = e&63;
    vbT[((size_t)h*64 + dv)*TT + t0 + tt] = __float2bfloat16(tbuf[tt][dv]);
  }
}

// ---------------- MFMA GEMM: C[m][n] = sum_k A[m][k]*B[n][k] ----------------
template<bool SPLIT, int KSPLIT, bool ATOMIC>
__global__ __launch_bounds__(256) void gemm_mfma_k(
    const __hip_bfloat16* __restrict__ Ah, const __hip_bfloat16* __restrict__ Al,
    const __hip_bfloat16* __restrict__ Bh, const __hip_bfloat16* __restrict__ Bl,
    float* __restrict__ Cc, int M, int N, int K)
{
  __shared__ __align__(16) char lds[2][32768];
  const int tid = threadIdx.x;
  const int nbx = N >> 7;
  const int tile = blockIdx.x / KSPLIT;
  const int ks = blockIdx.x - tile*KSPLIT;
  const int by = tile / nbx, bx = tile - by*nbx;
  const int m0 = by << 7, n0 = bx << 7;
  const int w = tid >> 6;
  const int l = tid & 63;
  const int wslot = w << 6;
  const int wi = w >> 1, wj = w & 1;
  const int fr = l & 15, fo = l >> 4;
  const int kw = SPLIT ? 32 : 64;
  const int nsteps = K / kw / KSPLIT;
  const int k0base = ks * (K / KSPLIT);

  f32x4 acc[4][4];
#pragma unroll
  for (int i = 0; i < 4; ++i)
#pragma unroll
    for (int j = 0; j < 4; ++j) acc[i][j] = f32x4{0.f,0.f,0.f,0.f};

  int srow[4], schg[4];
#pragma unroll
  for (int r = 0; r < 4; ++r) {
    int s = r*256 + tid;
    srow[r] = s >> 3;
    schg[r] = (s & 7) ^ ((s >> 3) & 7);
  }

  auto stageAB = [&](int buf, int st) {
    const int k0 = k0base + st * kw;
#pragma unroll
    for (int r = 0; r < 4; ++r) {
      const __hip_bfloat16 *pa, *pb;
      if (SPLIT) {
        pa = (schg[r] < 4 ? Ah : Al) + (size_t)(m0+srow[r])*K + k0 + (schg[r]&3)*8;
        pb = (schg[r] < 4 ? Bh : Bl) + (size_t)(n0+srow[r])*K + k0 + (schg[r]&3)*8;
      } else {
        pa = Ah + (size_t)(m0+srow[r])*K + k0 + schg[r]*8;
        pb = Bh + (size_t)(n0+srow[r])*K + k0 + schg[r]*8;
      }
      gload16(pa, lds[buf] + (r*256 + wslot)*16);
      gload16(pb, lds[buf] + 16384 + (r*256 + wslot)*16);
    }
  };

  stageAB(0, 0);
  __syncthreads();

  for (int st = 0; st < nsteps; ++st) {
    const int buf = st & 1;
    if (st + 1 < nsteps) stageAB(buf ^ 1, st + 1);
    char* ldsb = lds[buf];

    if (SPLIT) {
      bf16x8 bhf[4], blf[4];
#pragma unroll
      for (int j = 0; j < 4; ++j) {
        int row = wj*64 + j*16 + fr;
        bhf[j] = *(const bf16x8*)(ldsb + 16384 + row*128 + ((fo     ^ (row&7))*16));
        blf[j] = *(const bf16x8*)(ldsb + 16384 + row*128 + (((4+fo) ^ (row&7))*16));
      }
#pragma unroll
      for (int i = 0; i < 4; ++i) {
        int row = wi*64 + i*16 + fr;
        bf16x8 ah = *(const bf16x8*)(ldsb + row*128 + ((fo     ^ (row&7))*16));
        bf16x8 al = *(const bf16x8*)(ldsb + row*128 + (((4+fo) ^ (row&7))*16));
#pragma unroll
        for (int j = 0; j < 4; ++j) {
          acc[i][j] = __builtin_amdgcn_mfma_f32_16x16x32_bf16(al, bhf[j], acc[i][j], 0,0,0);
          acc[i][j] = __builtin_amdgcn_mfma_f32_16x16x32_bf16(ah, blf[j], acc[i][j], 0,0,0);
          acc[i][j] = __builtin_amdgcn_mfma_f32_16x16x32_bf16(ah, bhf[j], acc[i][j], 0,0,0);
        }
      }
    } else {
#pragma unroll
      for (int kk = 0; kk < 2; ++kk) {
        bf16x8 bf[4];
#pragma unroll
        for (int j = 0; j < 4; ++j) {
          int row = wj*64 + j*16 + fr;
          bf[j] = *(const bf16x8*)(ldsb + 16384 + row*128 + (((kk*4+fo) ^ (row&7))*16));
        }
#pragma unroll
        for (int i = 0; i < 4; ++i) {
          int row = wi*64 + i*16 + fr;
          bf16x8 af = *(const bf16x8*)(ldsb + row*128 + (((kk*4+fo) ^ (row&7))*16));
#pragma unroll
          for (int j = 0; j < 4; ++j)
            acc[i][j] = __builtin_amdgcn_mfma_f32_16x16x32_bf16(af, bf[j], acc[i][j], 0,0,0);
        }
      }
    }
    __syncthreads();
  }

  // epilogue: per-wave LDS transpose -> float4 row stores (or atomic adds)
  float* ep = (float*)((char*)lds + (size_t)w*8704);
#pragma unroll
  for (int pass = 0; pass < 2; ++pass) {
#pragma unroll
    for (int ii = 0; ii < 2; ++ii) {
      int i = pass*2 + ii;
#pragma unroll
      for (int j = 0; j < 4; ++j)
#pragma unroll
        for (int e = 0; e < 4; ++e)
          ep[(ii*16 + fo*4 + e)*68 + j*16 + fr] = acc[i][j][e];
    }
#pragma unroll
    for (int eidx = 0; eidx < 8; ++eidx) {
      int fi = eidx*64 + l;
      int row = fi >> 4, c4 = fi & 15;
      float4 v4 = *(const float4*)(ep + row*68 + c4*4);
      float* dst = Cc + (size_t)(m0 + wi*64 + pass*32 + row)*N + n0 + wj*64 + c4*4;
      if (ATOMIC) {
        atomicAdd(dst+0, v4.x); atomicAdd(dst+1, v4.y);
        atomicAdd(dst+2, v4.z); atomicAdd(dst+3, v4.w);
      } else {
        *(float4*)dst = v4;
      }
    }
  }
}

// ---------------- phase A: bf16 MFMA scoring, M-split occupancy, merged top-4 ----------------
__global__ __launch_bounds__(256) void knn_chunkmin_k(
    const __hip_bfloat16* __restrict__ kb, const __hip_bfloat16* __restrict__ ksb,
    const float* __restrict__ ksnb, unsigned int* __restrict__ cand)
{
  __shared__ __align__(16) char lds[32768];
  const int tid = threadIdx.x;
  const int bid = blockIdx.x;
  const int orig = (bid & 7)*128 + (bid >> 3);
  const int h  = orig >> 6;
  const int n0 = (orig & 63) * 32;
  const int w  = tid >> 6;
  const int wh = w >> 1;
  const int wr = w & 1;
  const int l  = tid & 63;
  const int cr = l & 15, hi = l >> 4;

  bf16x8 af0, af1;
  {
    const __hip_bfloat16* kbh = kb + (size_t)h*TT*64 + (size_t)(n0 + wr*16 + cr)*64;
    af0 = *reinterpret_cast<const bf16x8*>(kbh + hi*8);
    af1 = *reinterpret_cast<const bf16x8*>(kbh + 32 + hi*8);
  }
  const __hip_bfloat16* ksbh = ksb + (size_t)h*MM*64;
  const float* ksnh = ksnb + (size_t)h*MM;

  char* myhalf = lds + wh*16384;
  int gsrc[4];
#pragma unroll
  for (int r = 0; r < 4; ++r) {
    int s = r*128 + wr*64 + l;
    gsrc[r] = (s & ~7) | ((s & 7) ^ ((s >> 3) & 7));
  }
  const int rb0 = cr*128 + ((hi ^ (l&7))*16);
  const int rb1 = cr*128 + (((4+hi) ^ (l&7))*16);

  unsigned cnd[4][4];
#pragma unroll
  for (int i = 0; i < 4; ++i)
#pragma unroll
    for (int c = 0; c < 4; ++c) cnd[i][c] = 0xFFFFFFFFu;

  auto stage = [&](int buf, int tt) {
    const __hip_bfloat16* src = ksbh + ((size_t)(wh*64 + tt))*4096;
    char* dst = myhalf + buf*8192 + (wr << 10);
#pragma unroll
    for (int r = 0; r < 4; ++r)
      gload16(src + gsrc[r]*8, dst + (r << 11));
  };

  stage(0, 0);
  __syncthreads();

  for (int tt = 0; tt < 64; ++tt) {
    const int buf = tt & 1;
    if (tt + 1 < 64) stage(buf ^ 1, tt + 1);
    char* ldsb = myhalf + buf*8192;
    const int ttg = wh*64 + tt;
    const unsigned crtt = ((unsigned)cr << 7) | (unsigned)ttg;

    float kn0 = ksnh[ttg*64 +  0 + cr];
    float kn1 = ksnh[ttg*64 + 16 + cr];
    float kn2 = ksnh[ttg*64 + 32 + cr];
    float kn3 = ksnh[ttg*64 + 48 + cr];

    f32x4 acc[4];
#pragma unroll
    for (int b = 0; b < 4; ++b) {
      bf16x8 bf0 = *reinterpret_cast<const bf16x8*>(ldsb + b*2048 + rb0);
      bf16x8 bf1 = *reinterpret_cast<const bf16x8*>(ldsb + b*2048 + rb1);
      f32x4 z = {0.f, 0.f, 0.f, 0.f};
      z = __builtin_amdgcn_mfma_f32_16x16x32_bf16(af0, bf0, z, 0, 0, 0);
      z = __builtin_amdgcn_mfma_f32_16x16x32_bf16(af1, bf1, z, 0, 0, 0);
      acc[b] = z;
    }
#pragma unroll
    for (int i = 0; i < 4; ++i) {
      float s0 = fmaf(acc[0][i], -2.f, kn0);
      float s1 = fmaf(acc[1][i], -2.f, kn1);
      float s2 = fmaf(acc[2][i], -2.f, kn2);
      float s3 = fmaf(acc[3][i], -2.f, kn3);
      float m4 = fminf(fminf(s0, s1), fminf(s2, s3));
      unsigned x = (__float_as_uint(m4) & 0xFFFFF800u) | crtt;
      unsigned t0 = umn(cnd[i][0], x);
      unsigned t1 = umed3(x, cnd[i][0], cnd[i][1]);
      unsigned t2 = umed3(x, cnd[i][1], cnd[i][2]);
      unsigned t3 = umed3(x, cnd[i][2], cnd[i][3]);
      cnd[i][0] = t0; cnd[i][1] = t1; cnd[i][2] = t2; cnd[i][3] = t3;
    }
    __syncthreads();
  }

  uint4* sh = (uint4*)lds;
  if (wh == 1) {
#pragma unroll
    for (int i = 0; i < 4; ++i)
      sh[wr*256 + (hi*4+i)*16 + cr] = make_uint4(cnd[i][0], cnd[i][1], cnd[i][2], cnd[i][3]);
  }
  __syncthreads();
  if (wh == 0) {
#pragma unroll
    for (int i = 0; i < 4; ++i) {
      uint4 b = sh[wr*256 + (hi*4+i)*16 + cr];
      int n = n0 + wr*16 + hi*4 + i;
      reinterpret_cast<uint4*>(cand)[(size_t)(h*TT + n)*16 + cr] =
          make_uint4(umn(cnd[i][0], b.w), umn(cnd[i][1], b.z),
                     umn(cnd[i][2], b.y), umn(cnd[i][3], b.x));
    }
  }
}

// ---------------- fused phase B: 1 row/wave; 64-wide chunk sort + 32-wide rescore sort ----------------
__global__ __launch_bounds__(256) void knn_fused_k(
    const unsigned int* __restrict__ cand, const float* __restrict__ qkv,
    const float* __restrict__ kstore, const float* __restrict__ vstore,
    const float* __restrict__ ksn, const int* __restrict__ mask,
    float* __restrict__ vnew)
{
  const int row = blockIdx.x*4 + (threadIdx.x>>6);
  const int l = threadIdx.x & 63;
  const int ll = l & 31;
  const int h = row >> 11, t = row & (TT-1);
  const float* base = qkv + (size_t)t*C3 + h*64;
  float vh = base[2*CC + l];
  float* outp = vnew + (size_t)row*64;
  if (!mask[row]) { outp[l] = vh; return; }

  unsigned v = cand[(size_t)row*64 + l];
#pragma unroll
  for (int k = 2; k <= 64; k <<= 1)
#pragma unroll
    for (int j = k>>1; j > 0; j >>= 1) {
      unsigned o = __shfl_xor(v, j, 64);
      bool takeMin = ((l & j) == 0) == ((l & k) == 0);
      v = (takeMin == (o < v)) ? o : v;
    }

  const int c = l >> 1;
  const int b = c & 3;
  unsigned vc = __shfl(v, c >> 2, 64);
  const int m = ((int)(vc & 127u))*64 + b*16 + (int)((vc >> 7) & 15u);
  const int p = l & 1;
  unsigned kh, km;
  {
    const float* kq = base + CC + p*32;
    const float* ksr = kstore + ((size_t)h*MM + m)*64 + p*32;
    float dp = 0.f;
#pragma unroll
    for (int i = 0; i < 8; ++i) {
      float4 a = *(const float4*)(kq + i*4);
      float4 bb = *(const float4*)(ksr + i*4);
      dp = fmaf(a.x,bb.x, fmaf(a.y,bb.y, fmaf(a.z,bb.z, fmaf(a.w,bb.w, dp))));
    }
    dp += __shfl_xor(dp, 1, 64);
    float s = ksn[(size_t)h*MM + m] - 2.f*dp;
    unsigned u = __float_as_uint(s);
    unsigned skey = u ^ (unsigned)(((int)u >> 31) | 0x80000000);
    kh = __shfl(skey, 2*ll, 64);
    km = __shfl((unsigned)m, 2*ll, 64);
#pragma unroll
    for (int k = 2; k <= 32; k <<= 1)
#pragma unroll
      for (int j = k>>1; j > 0; j >>= 1) {
        unsigned oh = __shfl_xor(kh, j, 64);
        unsigned ol = __shfl_xor(km, j, 64);
        bool takeMin = ((ll & j) == 0) == ((ll & k) == 0);
        bool oLess = (oh < kh) || (oh == kh && ol < km);
        if (takeMin == oLess) { kh = oh; km = ol; }
      }
  }

  const int m0 = (int)__shfl(km, 0, 64);
  const int m1 = (int)__shfl(km, 1, 64);
  const int m2 = (int)__shfl(km, 2, 64);
  const int m3 = (int)__shfl(km, 3, 64);
  const int g = l >> 3, gl = l & 7;
  float dq = 0.f;
  if (g < 5) {
    int msel = (g == 0) ? m0 : (g == 1) ? m1 : (g == 2) ? m2 : m3;
    const float* qrow = base + gl*8;
    const float* kr = (g < 4) ? (kstore + ((size_t)h*MM + msel)*64 + gl*8)
                              : (base + CC + gl*8);
    float4 a0 = *(const float4*)(qrow);
    float4 a1 = *(const float4*)(qrow + 4);
    float4 b0 = *(const float4*)(kr);
    float4 b1 = *(const float4*)(kr + 4);
    dq = a0.x*b0.x + a0.y*b0.y + a0.z*b0.z + a0.w*b0.w
       + a1.x*b1.x + a1.y*b1.y + a1.z*b1.z + a1.w*b1.w;
  }
  dq += __shfl_xor(dq, 1, 64);
  dq += __shfl_xor(dq, 2, 64);
  dq += __shfl_xor(dq, 4, 64);
  float d0 = __shfl(dq,  0, 64)*0.125f;
  float d1 = __shfl(dq,  8, 64)*0.125f;
  float d2 = __shfl(dq, 16, 64)*0.125f;
  float d3 = __shfl(dq, 24, 64)*0.125f;
  float d4 = __shfl(dq, 32, 64)*0.125f;
  float mx = fmaxf(fmaxf(fmaxf(d0,d1),fmaxf(d2,d3)),d4);
  float w0 = __expf(d0-mx), w1 = __expf(d1-mx), w2 = __expf(d2-mx),
        w3 = __expf(d3-mx), w4 = __expf(d4-mx);
  float Z = w0+w1+w2+w3+w4;
  float vv = w4*vh
           + w0*vstore[((size_t)h*MM+m0)*64 + l]
           + w1*vstore[((size_t)h*MM+m1)*64 + l]
           + w2*vstore[((size_t)h*MM+m2)*64 + l]
           + w3*vstore[((size_t)h*MM+m3)*64 + l];
  outp[l] = 0.5f*(vv/Z) + 0.5f*vh;
}

// ---------------- bf16 MFMA flash attention, KV-split partial states ----------------
// grid (64, 16): n = 31 - (bx>>1) (heavy first), half = bx&1.
// half0 tiles [0, (n+2)>>1), half1 [(n+2)>>1, n+1). Writes fp32 (o, m, l) state.
__global__ __launch_bounds__(256) void attn_mfma_k(
    const float* __restrict__ qkv, const __hip_bfloat16* __restrict__ kb,
    const __hip_bfloat16* __restrict__ vbT, float* __restrict__ pso,
    float2* __restrict__ psml)
{
  __shared__ __align__(16) char lds[40960];
  const int h = blockIdx.y, bx = blockIdx.x, tid = threadIdx.x;
  const int w = tid>>6, l = tid&63, fr = l&15, fo = l>>4;
  const int wslot = w << 6;
  const __hip_bfloat16* kbh = kb + (size_t)h*TT*64;
  const __hip_bfloat16* vbh = vbT + (size_t)h*64*TT;
  char* Pt = lds + 32768 + w*2048;

  int srow[2], schg[2];
#pragma unroll
  for (int r = 0; r < 2; ++r) {
    int s = r*256 + tid;
    srow[r] = s >> 3;
    schg[r] = (s & 7) ^ ((s >> 3) & 7);
  }

  auto stageKV = [&](int buf, int kt) {
#pragma unroll
    for (int r = 0; r < 2; ++r) {
      gload16(kbh + (size_t)(kt*64 + srow[r])*64 + schg[r]*8,
              lds + buf*16384 + (r*256 + wslot)*16);
      gload16(vbh + (size_t)srow[r]*TT + kt*64 + schg[r]*8,
              lds + buf*16384 + 8192 + (r*256 + wslot)*16);
    }
  };

  const int n = 31 - (bx >> 1);
  const int hf = bx & 1;
  const int c1 = (n + 2) >> 1;
  const int t0 = hf ? c1 : 0;
  const int t1 = hf ? (n + 1) : c1;
  const int q0 = n * 64;

  bf16x8 qa[2];
  {
    const float* qrow = qkv + (size_t)(q0 + w*16 + fr)*C3 + h*64;
#pragma unroll
    for (int kk = 0; kk < 2; ++kk) {
      float4 u0 = *(const float4*)(qrow + kk*32 + fo*8);
      float4 u1 = *(const float4*)(qrow + kk*32 + fo*8 + 4);
      bf16x8 t;
      t[0]=(__bf16)u0.x; t[1]=(__bf16)u0.y; t[2]=(__bf16)u0.z; t[3]=(__bf16)u0.w;
      t[4]=(__bf16)u1.x; t[5]=(__bf16)u1.y; t[6]=(__bf16)u1.z; t[7]=(__bf16)u1.w;
      qa[kk] = t;
    }
  }
  float mrow[4], lsum[4];
  f32x4 oacc[4];
#pragma unroll
  for (int e = 0; e < 4; ++e) { mrow[e] = -INFINITY; lsum[e] = 0.f; }
#pragma unroll
  for (int jv = 0; jv < 4; ++jv) oacc[jv] = f32x4{0.f,0.f,0.f,0.f};

  if (t0 < t1) {
    stageKV(0, t0);
    __syncthreads();

    for (int kt = t0; kt < t1; ++kt) {
      const int buf = (kt - t0) & 1;
      if (kt + 1 < t1) stageKV(buf ^ 1, kt + 1);
      char* Kt = lds + buf*16384;
      char* Vt = Kt + 8192;

      f32x4 sv[4];
#pragma unroll
      for (int j = 0; j < 4; ++j) {
        int row = j*16 + fr;
        bf16x8 k0f = *(const bf16x8*)(Kt + row*128 + ((fo     ^ (row&7))*16));
        bf16x8 k1f = *(const bf16x8*)(Kt + row*128 + (((4+fo) ^ (row&7))*16));
        f32x4 z = {0.f,0.f,0.f,0.f};
        z = __builtin_amdgcn_mfma_f32_16x16x32_bf16(qa[0], k0f, z, 0,0,0);
        z = __builtin_amdgcn_mfma_f32_16x16x32_bf16(qa[1], k1f, z, 0,0,0);
        sv[j] = z;
      }
      if (kt == n) {
#pragma unroll
        for (int j = 0; j < 4; ++j)
#pragma unroll
          for (int e = 0; e < 4; ++e)
            sv[j][e] = (j*16 + fr <= w*16 + fo*4 + e) ? sv[j][e]*0.125f : -INFINITY;
      } else {
#pragma unroll
        for (int j = 0; j < 4; ++j)
#pragma unroll
          for (int e = 0; e < 4; ++e) sv[j][e] *= 0.125f;
      }
      float rmax[4];
#pragma unroll
      for (int e = 0; e < 4; ++e)
        rmax[e] = fmaxf(fmaxf(sv[0][e], sv[1][e]), fmaxf(sv[2][e], sv[3][e]));
#pragma unroll
      for (int off = 1; off < 16; off <<= 1)
#pragma unroll
        for (int e = 0; e < 4; ++e) rmax[e] = fmaxf(rmax[e], __shfl_xor(rmax[e], off, 64));
      float scl[4];
#pragma unroll
      for (int e = 0; e < 4; ++e) {
        float mn = fmaxf(mrow[e], rmax[e]);
        scl[e] = __expf(mrow[e] - mn);
        mrow[e] = mn;
      }
      float rsum[4] = {0.f,0.f,0.f,0.f};
#pragma unroll
      for (int j = 0; j < 4; ++j) {
        int chunkbase = j*2 + (fr>>3);
        int kvoff = (fr&7)*2;
#pragma unroll
        for (int e = 0; e < 4; ++e) {
          float p = __expf(sv[j][e] - mrow[e]);
          rsum[e] += p;
          int qloc = fo*4 + e;
          *(__bf16*)(Pt + qloc*128 + ((chunkbase ^ (qloc&7))*16) + kvoff) = (__bf16)p;
        }
      }
#pragma unroll
      for (int off = 1; off < 16; off <<= 1)
#pragma unroll
        for (int e = 0; e < 4; ++e) rsum[e] += __shfl_xor(rsum[e], off, 64);
#pragma unroll
      for (int e = 0; e < 4; ++e) lsum[e] = lsum[e]*scl[e] + rsum[e];
#pragma unroll
      for (int jv = 0; jv < 4; ++jv)
#pragma unroll
        for (int e = 0; e < 4; ++e) oacc[jv][e] *= scl[e];

      bf16x8 pa0 = *(const bf16x8*)(Pt + fr*128 + ((fo     ^ (fr&7))*16));
      bf16x8 pa1 = *(const bf16x8*)(Pt + fr*128 + (((4+fo) ^ (fr&7))*16));
#pragma unroll
      for (int jv = 0; jv < 4; ++jv) {
        int row = jv*16 + fr;
        bf16x8 v0f = *(const bf16x8*)(Vt + row*128 + ((fo     ^ (row&7))*16));
        bf16x8 v1f = *(const bf16x8*)(Vt + row*128 + (((4+fo) ^ (row&7))*16));
        oacc[jv] = __builtin_amdgcn_mfma_f32_16x16x32_bf16(pa0, v0f, oacc[jv], 0,0,0);
        oacc[jv] = __builtin_amdgcn_mfma_f32_16x16x32_bf16(pa1, v1f, oacc[jv], 0,0,0);
      }
      __syncthreads();
    }
  }

  // epilogue: write partial state
  float* po = pso + ((size_t)hf*HH + h)*32*4096 + (size_t)n*4096;
  float2* pm = psml + ((size_t)hf*HH + h)*2048 + (size_t)n*64;
#pragma unroll
  for (int jv = 0; jv < 4; ++jv)
#pragma unroll
    for (int e = 0; e < 4; ++e) {
      int qloc = w*16 + fo*4 + e;
      po[qloc*64 + jv*16 + fr] = oacc[jv][e];
    }
#pragma unroll
  for (int e = 0; e < 4; ++e) {
    if (fr == 0) pm[w*16 + fo*4 + e] = make_float2(mrow[e], lsum[e]);
  }
}

// combine two partial flash states -> yb bf16
__global__ __launch_bounds__(256) void attn_combine_k(
    const float* __restrict__ pso, const float2* __restrict__ psml,
    __hip_bfloat16* __restrict__ yb)
{
  const int row = blockIdx.x*4 + (threadIdx.x>>6);   // HH*TT rows
  const int l = threadIdx.x & 63;
  const int h = row >> 11, t = row & (TT-1);
  const int n = t >> 6, q = t & 63;
  size_t ob = ((size_t)h*32 + n)*4096 + (size_t)q*64;
  size_t mb = ((size_t)h*32 + n)*64 + q;
  float o1 = pso[ob + l];
  float o2 = pso[(size_t)HH*32*4096 + ob + l];
  float2 ml1 = psml[mb];
  float2 ml2 = psml[(size_t)HH*32*64 + mb];
  float M = fmaxf(ml1.x, ml2.x);
  float e1 = __expf(ml1.x - M), e2 = __expf(ml2.x - M);
  float y = (e1*o1 + e2*o2) / (e1*ml1.y + e2*ml2.y);
  yb[(size_t)t*CC + h*64 + l] = __float2bfloat16(y);
}

extern "C" void kernel_launch(void* const* d_in, const int* in_sizes, int n_in,
                              void* d_out, int out_size, void* d_ws, size_t ws_size,
                              hipStream_t stream) {
  const float* x   = (const float*)d_in[0];
  const float* wat = (const float*)d_in[1];
  const float* wpr = (const float*)d_in[2];
  const float* kst = (const float*)d_in[3];
  const float* vst = (const float*)d_in[4];
  float* out = (float*)d_out;

  float* ws    = (float*)d_ws;
  float* qkv   = ws;                                   // 6291456
  float* ksn   = qkv + (size_t)6291456;                // 131072
  float* ksnb  = ksn + 131072;                         // 131072
  int*   idxb  = (int*)(ksnb + 131072);                // 131072 (reserved)
  int*   maskb = idxb + 131072;                        // 32768
  __hip_bfloat16* kb = (__hip_bfloat16*)(maskb + 32768);       // 1048576 fs
  float* candRegion = (float*)kb + 1048576;            // 2097152 fs (cand u32 / vnew f32 / yb bf16)
  unsigned int* candb = (unsigned int*)candRegion;
  float* vnew = candRegion;
  __hip_bfloat16* yb = (__hip_bfloat16*)candRegion;    // alias (after vtrans)
  __hip_bfloat16* vbT = (__hip_bfloat16*)(candRegion + 2097152); // 1048576 fs
  float* split = candRegion + 2097152 + 1048576;       // 5242880 fs region
  __hip_bfloat16* xhi = (__hip_bfloat16*)split;
  __hip_bfloat16* xlo = xhi + 2097152;
  __hip_bfloat16* whi = xlo + 2097152;
  __hip_bfloat16* wlo = whi + 3145728;
  __hip_bfloat16* ksb  = (__hip_bfloat16*)split;       // alias (after qkv GEMM)
  __hip_bfloat16* wprb = ksb + 8388608;                // persistent
  float* pso  = split;                                  // alias (after chunkmin): 4194304 fs
  float2* psml = (float2*)(split + 4718592);            // after wprb: 131072 float2

  // 1. conversions: x and wat hi/lo splits (one launch)
  mega1_k<<<dim3(2560), 256, 0, stream>>>(x, xhi, xlo, wat, whi, wlo);
  // 2. qkv = x @ c_attn_w^T (fp32-fidelity split MFMA)
  gemm_mfma_k<true,1,false><<<dim3(16*24), 256, 0, stream>>>(xhi, xlo, whi, wlo, qkv, TT, C3, CC);
  // 3. mask + key_store conv + k->bf16 + wpr->bf16 (one launch)
  mega2_k<<<dim3(3600), 256, 0, stream>>>(qkv, maskb, kst, ksb, ksn, ksnb, kb, wpr, wprb);
  // 4. phase A: MFMA chunk-min scoring
  knn_chunkmin_k<<<dim3(1024), 256, 0, stream>>>(kb, ksb, ksnb, candb);
  // 5. phase B fused: rescore -> top-4 -> v_new
  knn_fused_k<<<dim3(HH*TT/4), 256, 0, stream>>>(candb, qkv, kst, vst, ksn, maskb, vnew);
  // 6. v_new -> transposed bf16
  vtrans_k<<<dim3(32, HH), 256, 0, stream>>>(vnew, vbT);
  // 7. flash attention, KV-split partial states (4 blocks/CU)
  attn_mfma_k<<<dim3(64, HH), 256, 0, stream>>>(qkv, kb, vbT, pso, psml);
  // 8. combine states -> yb (in candRegion; vnew consumed)
  attn_combine_k<<<dim3(HH*TT/4), 256, 0, stream>>>(pso, psml, yb);
  // 9. out = y @ c_proj_w^T (K-split 2, atomic accumulate)
  hipMemsetAsync(out, 0, (size_t)out_size*sizeof(float), stream);
  gemm_mfma_k<false,2,true><<<dim3(256), 256, 0, stream>>>(yb, nullptr, wprb, nullptr, out, TT, CC, CC);
}

// Round 15
// 290.487 us; speedup vs baseline: 1.1852x; 1.1852x over previous
//
#include <hip/hip_runtime.h>
#include <hip/hip_bf16.h>
#include <math.h>

#define TT 2048
#define CC 1024
#define HH 16
#define DDIM 64
#define MM 8192
#define C3 3072
#define SBIAS 256.0f

typedef __bf16 bf16x8 __attribute__((ext_vector_type(8)));
typedef float f32x4 __attribute__((ext_vector_type(4)));

__device__ __forceinline__ float waveReduceSum(float v) {
#pragma unroll
  for (int off = 32; off > 0; off >>= 1) v += __shfl_xor(v, off, 64);
  return v;
}
__device__ __forceinline__ unsigned umn(unsigned a, unsigned b){ return a<b?a:b; }
__device__ __forceinline__ unsigned umed3(unsigned a, unsigned b, unsigned c){
  unsigned d;
  asm("v_med3_u32 %0, %1, %2, %3" : "=v"(d) : "v"(a), "v"(b), "v"(c));
  return d;
}

// async global->LDS, 16B per lane (linear dest, per-lane src carries swizzle)
__device__ __forceinline__ void gload16(const void* g, void* l) {
  __builtin_amdgcn_global_load_lds(
      (const __attribute__((address_space(1))) unsigned int*)g,
      (__attribute__((address_space(3))) unsigned int*)l, 16, 0, 0);
}

// ---------------- conversion bodies ----------------
__device__ __forceinline__ void conv_split_body(const float* __restrict__ src,
    __hip_bfloat16* __restrict__ hi, __hip_bfloat16* __restrict__ lo, size_t i)
{
  const float4* p = (const float4*)(src + i*8);
  float4 a = p[0], b = p[1];
  float v[8] = {a.x,a.y,a.z,a.w,b.x,b.y,b.z,b.w};
  bf16x8 H, L;
#pragma unroll
  for (int e = 0; e < 8; ++e) {
    __bf16 hb = (__bf16)v[e];
    H[e] = hb;
    L[e] = (__bf16)(v[e] - (float)hb);
  }
  *reinterpret_cast<bf16x8*>(hi + i*8) = H;
  *reinterpret_cast<bf16x8*>(lo + i*8) = L;
}

__device__ __forceinline__ void conv_bf16_body(const float* __restrict__ src,
    __hip_bfloat16* __restrict__ dst, size_t i)
{
  const float4* p = (const float4*)(src + i*8);
  float4 a = p[0], b = p[1];
  float v[8] = {a.x,a.y,a.z,a.w,b.x,b.y,b.z,b.w};
  bf16x8 H;
#pragma unroll
  for (int e = 0; e < 8; ++e) H[e] = (__bf16)v[e];
  *reinterpret_cast<bf16x8*>(dst + i*8) = H;
}

// mega1: conv_split(x) [0,1024) | conv_split(wat) [1024,2560)
__global__ __launch_bounds__(256) void mega1_k(
    const float* __restrict__ x, __hip_bfloat16* __restrict__ xhi, __hip_bfloat16* __restrict__ xlo,
    const float* __restrict__ wat, __hip_bfloat16* __restrict__ whi, __hip_bfloat16* __restrict__ wlo)
{
  int bid = blockIdx.x;
  if (bid < 1024) conv_split_body(x, xhi, xlo, (size_t)bid*256 + threadIdx.x);
  else            conv_split_body(wat, whi, wlo, (size_t)(bid-1024)*256 + threadIdx.x);
}

// mega2: mask [0,16) | conv_ks [16,2064) | conv_kb [2064,3088) | conv wpr [3088,3600)
__global__ __launch_bounds__(256) void mega2_k(
    const float* __restrict__ qkv, int* __restrict__ mask,
    const float* __restrict__ kst, __hip_bfloat16* __restrict__ ksb,
    float* __restrict__ ksn, float* __restrict__ ksnb,
    __hip_bfloat16* __restrict__ kb,
    const float* __restrict__ wpr, __hip_bfloat16* __restrict__ wprb)
{
  __shared__ float sm[64 + TT + 256];
  const int bid = blockIdx.x;
  const int tid = threadIdx.x;
  if (bid < 16) {
    const int h = bid;
    float* ql = sm;
    float* lg = sm + 64;
    float* red = sm + 64 + TT;
    if (tid < 64) ql[tid] = qkv[(size_t)(TT-1)*C3 + h*DDIM + tid];
    __syncthreads();
    float lmax = -INFINITY;
    for (int t = tid; t < TT; t += 256) {
      const float* kr = qkv + (size_t)t*C3 + CC + h*DDIM;
      float s = 0.f;
#pragma unroll
      for (int d = 0; d < 64; ++d) s += ql[d] * kr[d];
      s *= 0.125f;
      lg[t] = s;
      lmax = fmaxf(lmax, s);
    }
    red[tid] = lmax; __syncthreads();
    for (int off = 128; off > 0; off >>= 1) { if (tid < off) red[tid] = fmaxf(red[tid], red[tid+off]); __syncthreads(); }
    float mx = red[0];
    __syncthreads();
    float ls = 0.f;
    for (int t = tid; t < TT; t += 256) { float e = expf(lg[t]-mx); lg[t] = e; ls += e; }
    red[tid] = ls; __syncthreads();
    for (int off = 128; off > 0; off >>= 1) { if (tid < off) red[tid] += red[tid+off]; __syncthreads(); }
    float Z = red[0];
    for (int t = tid; t < TT; t += 256) mask[h*TT + t] = (lg[t]/Z >= 1.220703125e-4f) ? 1 : 0;
  } else if (bid < 2064) {
    int row = (bid - 16)*64 + (tid >> 2);
    int q = tid & 3;
    const float* src = kst + (size_t)row*64 + q*16;
    float s = 0.f;
    bf16x8 H0, H1;
#pragma unroll
    for (int i = 0; i < 2; ++i) {
      float4 a = ((const float4*)src)[i*2];
      float4 b = ((const float4*)src)[i*2+1];
      s += a.x*a.x + a.y*a.y + a.z*a.z + a.w*a.w
         + b.x*b.x + b.y*b.y + b.z*b.z + b.w*b.w;
      bf16x8 H;
      H[0]=(__bf16)a.x; H[1]=(__bf16)a.y; H[2]=(__bf16)a.z; H[3]=(__bf16)a.w;
      H[4]=(__bf16)b.x; H[5]=(__bf16)b.y; H[6]=(__bf16)b.z; H[7]=(__bf16)b.w;
      if (i == 0) H0 = H; else H1 = H;
    }
    s += __shfl_xor(s, 1, 64);
    s += __shfl_xor(s, 2, 64);
    *reinterpret_cast<bf16x8*>(ksb + (size_t)row*64 + q*16)     = H0;
    *reinterpret_cast<bf16x8*>(ksb + (size_t)row*64 + q*16 + 8) = H1;
    if (q == 0) { ksn[row] = s; ksnb[row] = s + SBIAS; }
  } else if (bid < 3088) {
    int e = (bid - 2064)*256 + tid;
    int dg = e & 7; int t = (e>>3) & (TT-1); int h = e >> 14;
    const float* src = qkv + (size_t)t*C3 + CC + h*64 + dg*8;
    __hip_bfloat16* dst = kb + ((size_t)(h*TT + t)*64 + dg*8);
#pragma unroll
    for (int i = 0; i < 8; ++i) dst[i] = __float2bfloat16(src[i]);
  } else {
    conv_bf16_body(wpr, wprb, (size_t)(bid - 3088)*256 + tid);
  }
}

// vnew [h*TT+t][dv] fp32 -> vbT [h][dv][t] bf16
__global__ __launch_bounds__(256) void vtrans_k(const float* __restrict__ vnew,
    __hip_bfloat16* __restrict__ vbT)
{
  __shared__ float tbuf[64][65];
  const int h = blockIdx.y, t0 = blockIdx.x*64, tid = threadIdx.x;
#pragma unroll
  for (int r = 0; r < 16; ++r) {
    int e = r*256 + tid; int row = e>>6, dv = e&63;
    tbuf[row][dv] = vnew[((size_t)h*TT + t0 + row)*64 + dv];
  }
  __syncthreads();
#pragma unroll
  for (int r = 0; r < 16; ++r) {
    int e = r*256 + tid; int dv = e>>6, tt = e&63;
    vbT[((size_t)h*64 + dv)*TT + t0 + tt] = __float2bfloat16(tbuf[tt][dv]);
  }
}

// ---------------- MFMA GEMM: C[m][n] = sum_k A[m][k]*B[n][k] ----------------
template<bool SPLIT>
__global__ __launch_bounds__(256) void gemm_mfma_k(
    const __hip_bfloat16* __restrict__ Ah, const __hip_bfloat16* __restrict__ Al,
    const __hip_bfloat16* __restrict__ Bh, const __hip_bfloat16* __restrict__ Bl,
    float* __restrict__ Cc, int M, int N, int K)
{
  __shared__ __align__(16) char lds[2][32768];
  const int tid = threadIdx.x;
  const int nbx = N >> 7;
  const int by = blockIdx.x / nbx, bx = blockIdx.x - by*nbx;
  const int m0 = by << 7, n0 = bx << 7;
  const int w = tid >> 6;
  const int l = tid & 63;
  const int wslot = w << 6;
  const int wi = w >> 1, wj = w & 1;
  const int fr = l & 15, fo = l >> 4;
  const int kw = SPLIT ? 32 : 64;
  const int nsteps = K / kw;

  f32x4 acc[4][4];
#pragma unroll
  for (int i = 0; i < 4; ++i)
#pragma unroll
    for (int j = 0; j < 4; ++j) acc[i][j] = f32x4{0.f,0.f,0.f,0.f};

  int srow[4], schg[4];
#pragma unroll
  for (int r = 0; r < 4; ++r) {
    int s = r*256 + tid;
    srow[r] = s >> 3;
    schg[r] = (s & 7) ^ ((s >> 3) & 7);
  }

  auto stageAB = [&](int buf, int st) {
    const int k0 = st * kw;
#pragma unroll
    for (int r = 0; r < 4; ++r) {
      const __hip_bfloat16 *pa, *pb;
      if (SPLIT) {
        pa = (schg[r] < 4 ? Ah : Al) + (size_t)(m0+srow[r])*K + k0 + (schg[r]&3)*8;
        pb = (schg[r] < 4 ? Bh : Bl) + (size_t)(n0+srow[r])*K + k0 + (schg[r]&3)*8;
      } else {
        pa = Ah + (size_t)(m0+srow[r])*K + k0 + schg[r]*8;
        pb = Bh + (size_t)(n0+srow[r])*K + k0 + schg[r]*8;
      }
      gload16(pa, lds[buf] + (r*256 + wslot)*16);
      gload16(pb, lds[buf] + 16384 + (r*256 + wslot)*16);
    }
  };

  stageAB(0, 0);
  __syncthreads();

  for (int st = 0; st < nsteps; ++st) {
    const int buf = st & 1;
    if (st + 1 < nsteps) stageAB(buf ^ 1, st + 1);
    char* ldsb = lds[buf];

    if (SPLIT) {
      bf16x8 bhf[4], blf[4];
#pragma unroll
      for (int j = 0; j < 4; ++j) {
        int row = wj*64 + j*16 + fr;
        bhf[j] = *(const bf16x8*)(ldsb + 16384 + row*128 + ((fo     ^ (row&7))*16));
        blf[j] = *(const bf16x8*)(ldsb + 16384 + row*128 + (((4+fo) ^ (row&7))*16));
      }
#pragma unroll
      for (int i = 0; i < 4; ++i) {
        int row = wi*64 + i*16 + fr;
        bf16x8 ah = *(const bf16x8*)(ldsb + row*128 + ((fo     ^ (row&7))*16));
        bf16x8 al = *(const bf16x8*)(ldsb + row*128 + (((4+fo) ^ (row&7))*16));
#pragma unroll
        for (int j = 0; j < 4; ++j) {
          acc[i][j] = __builtin_amdgcn_mfma_f32_16x16x32_bf16(al, bhf[j], acc[i][j], 0,0,0);
          acc[i][j] = __builtin_amdgcn_mfma_f32_16x16x32_bf16(ah, blf[j], acc[i][j], 0,0,0);
          acc[i][j] = __builtin_amdgcn_mfma_f32_16x16x32_bf16(ah, bhf[j], acc[i][j], 0,0,0);
        }
      }
    } else {
#pragma unroll
      for (int kk = 0; kk < 2; ++kk) {
        bf16x8 bf[4];
#pragma unroll
        for (int j = 0; j < 4; ++j) {
          int row = wj*64 + j*16 + fr;
          bf[j] = *(const bf16x8*)(ldsb + 16384 + row*128 + (((kk*4+fo) ^ (row&7))*16));
        }
#pragma unroll
        for (int i = 0; i < 4; ++i) {
          int row = wi*64 + i*16 + fr;
          bf16x8 af = *(const bf16x8*)(ldsb + row*128 + (((kk*4+fo) ^ (row&7))*16));
#pragma unroll
          for (int j = 0; j < 4; ++j)
            acc[i][j] = __builtin_amdgcn_mfma_f32_16x16x32_bf16(af, bf[j], acc[i][j], 0,0,0);
        }
      }
    }
    __syncthreads();
  }

  // epilogue: per-wave LDS transpose -> float4 row stores
  float* ep = (float*)((char*)lds + (size_t)w*8704);
#pragma unroll
  for (int pass = 0; pass < 2; ++pass) {
#pragma unroll
    for (int ii = 0; ii < 2; ++ii) {
      int i = pass*2 + ii;
#pragma unroll
      for (int j = 0; j < 4; ++j)
#pragma unroll
        for (int e = 0; e < 4; ++e)
          ep[(ii*16 + fo*4 + e)*68 + j*16 + fr] = acc[i][j][e];
    }
#pragma unroll
    for (int eidx = 0; eidx < 8; ++eidx) {
      int fi = eidx*64 + l;
      int row = fi >> 4, c4 = fi & 15;
      float4 v4 = *(const float4*)(ep + row*68 + c4*4);
      *(float4*)(Cc + (size_t)(m0 + wi*64 + pass*32 + row)*N + n0 + wj*64 + c4*4) = v4;
    }
  }
}

// ---------------- phase A: bf16 MFMA scoring, M-split occupancy, merged top-4 ----------------
__global__ __launch_bounds__(256) void knn_chunkmin_k(
    const __hip_bfloat16* __restrict__ kb, const __hip_bfloat16* __restrict__ ksb,
    const float* __restrict__ ksnb, unsigned int* __restrict__ cand)
{
  __shared__ __align__(16) char lds[32768];   // 2 halves x 2 bufs x 8KB
  const int tid = threadIdx.x;
  const int bid = blockIdx.x;
  const int orig = (bid & 7)*128 + (bid >> 3);   // XCD-chunked swizzle (1024 = 8*128)
  const int h  = orig >> 6;
  const int n0 = (orig & 63) * 32;
  const int w  = tid >> 6;
  const int wh = w >> 1;        // tile-half
  const int wr = w & 1;         // row-half
  const int l  = tid & 63;
  const int cr = l & 15, hi = l >> 4;

  bf16x8 af0, af1;
  {
    const __hip_bfloat16* kbh = kb + (size_t)h*TT*64 + (size_t)(n0 + wr*16 + cr)*64;
    af0 = *reinterpret_cast<const bf16x8*>(kbh + hi*8);
    af1 = *reinterpret_cast<const bf16x8*>(kbh + 32 + hi*8);
  }
  const __hip_bfloat16* ksbh = ksb + (size_t)h*MM*64;
  const float* ksnh = ksnb + (size_t)h*MM;

  char* myhalf = lds + wh*16384;
  int gsrc[4];
#pragma unroll
  for (int r = 0; r < 4; ++r) {
    int s = r*128 + wr*64 + l;
    gsrc[r] = (s & ~7) | ((s & 7) ^ ((s >> 3) & 7));
  }
  const int rb0 = cr*128 + ((hi ^ (l&7))*16);
  const int rb1 = cr*128 + (((4+hi) ^ (l&7))*16);

  unsigned cnd[4][4];
#pragma unroll
  for (int i = 0; i < 4; ++i)
#pragma unroll
    for (int c = 0; c < 4; ++c) cnd[i][c] = 0xFFFFFFFFu;

  auto stage = [&](int buf, int tt) {
    const __hip_bfloat16* src = ksbh + ((size_t)(wh*64 + tt))*4096;
    char* dst = myhalf + buf*8192 + (wr << 10);
#pragma unroll
    for (int r = 0; r < 4; ++r)
      gload16(src + gsrc[r]*8, dst + (r << 11));
  };

  stage(0, 0);
  __syncthreads();

  for (int tt = 0; tt < 64; ++tt) {
    const int buf = tt & 1;
    if (tt + 1 < 64) stage(buf ^ 1, tt + 1);
    char* ldsb = myhalf + buf*8192;
    const int ttg = wh*64 + tt;
    const unsigned crtt = ((unsigned)cr << 7) | (unsigned)ttg;

    float kn0 = ksnh[ttg*64 +  0 + cr];
    float kn1 = ksnh[ttg*64 + 16 + cr];
    float kn2 = ksnh[ttg*64 + 32 + cr];
    float kn3 = ksnh[ttg*64 + 48 + cr];

    f32x4 acc[4];
#pragma unroll
    for (int b = 0; b < 4; ++b) {
      bf16x8 bf0 = *reinterpret_cast<const bf16x8*>(ldsb + b*2048 + rb0);
      bf16x8 bf1 = *reinterpret_cast<const bf16x8*>(ldsb + b*2048 + rb1);
      f32x4 z = {0.f, 0.f, 0.f, 0.f};
      z = __builtin_amdgcn_mfma_f32_16x16x32_bf16(af0, bf0, z, 0, 0, 0);
      z = __builtin_amdgcn_mfma_f32_16x16x32_bf16(af1, bf1, z, 0, 0, 0);
      acc[b] = z;
    }
#pragma unroll
    for (int i = 0; i < 4; ++i) {
      float s0 = fmaf(acc[0][i], -2.f, kn0);
      float s1 = fmaf(acc[1][i], -2.f, kn1);
      float s2 = fmaf(acc[2][i], -2.f, kn2);
      float s3 = fmaf(acc[3][i], -2.f, kn3);
      float m4 = fminf(fminf(s0, s1), fminf(s2, s3));
      unsigned x = (__float_as_uint(m4) & 0xFFFFF800u) | crtt;
      unsigned t0 = umn(cnd[i][0], x);
      unsigned t1 = umed3(x, cnd[i][0], cnd[i][1]);
      unsigned t2 = umed3(x, cnd[i][1], cnd[i][2]);
      unsigned t3 = umed3(x, cnd[i][2], cnd[i][3]);
      cnd[i][0] = t0; cnd[i][1] = t1; cnd[i][2] = t2; cnd[i][3] = t3;
    }
    __syncthreads();
  }

  // merge epilogue: half1 publishes sorted top-4; half0 bitonic-merges (min(a_i,b_{3-i}))
  uint4* sh = (uint4*)lds;   // [wr][16 rows][16 cr]
  if (wh == 1) {
#pragma unroll
    for (int i = 0; i < 4; ++i)
      sh[wr*256 + (hi*4+i)*16 + cr] = make_uint4(cnd[i][0], cnd[i][1], cnd[i][2], cnd[i][3]);
  }
  __syncthreads();
  if (wh == 0) {
#pragma unroll
    for (int i = 0; i < 4; ++i) {
      uint4 b = sh[wr*256 + (hi*4+i)*16 + cr];
      int n = n0 + wr*16 + hi*4 + i;
      reinterpret_cast<uint4*>(cand)[(size_t)(h*TT + n)*16 + cr] =
          make_uint4(umn(cnd[i][0], b.w), umn(cnd[i][1], b.z),
                     umn(cnd[i][2], b.y), umn(cnd[i][3], b.x));
    }
  }
}

// ---------------- fused phase B: 1 row/wave; 64-wide chunk sort + 32-wide rescore sort ----------------
__global__ __launch_bounds__(256) void knn_fused_k(
    const unsigned int* __restrict__ cand, const float* __restrict__ qkv,
    const float* __restrict__ kstore, const float* __restrict__ vstore,
    const float* __restrict__ ksn, const int* __restrict__ mask,
    float* __restrict__ vnew)
{
  const int row = blockIdx.x*4 + (threadIdx.x>>6);
  const int l = threadIdx.x & 63;
  const int ll = l & 31;
  const int h = row >> 11, t = row & (TT-1);
  const float* base = qkv + (size_t)t*C3 + h*64;
  float vh = base[2*CC + l];
  float* outp = vnew + (size_t)row*64;
  if (!mask[row]) { outp[l] = vh; return; }

  // stage 1: top-8 chunks of 64 packed values (ascending bitonic sort)
  unsigned v = cand[(size_t)row*64 + l];
#pragma unroll
  for (int k = 2; k <= 64; k <<= 1)
#pragma unroll
    for (int j = k>>1; j > 0; j >>= 1) {
      unsigned o = __shfl_xor(v, j, 64);
      bool takeMin = ((l & j) == 0) == ((l & k) == 0);
      v = (takeMin == (o < v)) ? o : v;
    }

  // stage 2: expand 8 chunks -> 32 candidates; exact fp32 k-dot, 2 lanes/cand
  const int c = l >> 1;
  const int b = c & 3;
  unsigned vc = __shfl(v, c >> 2, 64);
  const int m = ((int)(vc & 127u))*64 + b*16 + (int)((vc >> 7) & 15u);
  const int p = l & 1;
  unsigned kh, km;
  {
    const float* kq = base + CC + p*32;
    const float* ksr = kstore + ((size_t)h*MM + m)*64 + p*32;
    float dp = 0.f;
#pragma unroll
    for (int i = 0; i < 8; ++i) {
      float4 a = *(const float4*)(kq + i*4);
      float4 bb = *(const float4*)(ksr + i*4);
      dp = fmaf(a.x,bb.x, fmaf(a.y,bb.y, fmaf(a.z,bb.z, fmaf(a.w,bb.w, dp))));
    }
    dp += __shfl_xor(dp, 1, 64);
    float s = ksn[(size_t)h*MM + m] - 2.f*dp;
    unsigned u = __float_as_uint(s);
    unsigned skey = u ^ (unsigned)(((int)u >> 31) | 0x80000000);
    kh = __shfl(skey, 2*ll, 64);
    km = __shfl((unsigned)m, 2*ll, 64);
#pragma unroll
    for (int k = 2; k <= 32; k <<= 1)
#pragma unroll
      for (int j = k>>1; j > 0; j >>= 1) {
        unsigned oh = __shfl_xor(kh, j, 64);
        unsigned ol = __shfl_xor(km, j, 64);
        bool takeMin = ((ll & j) == 0) == ((ll & k) == 0);
        bool oLess = (oh < kh) || (oh == kh && ol < km);
        if (takeMin == oLess) { kh = oh; km = ol; }
      }
  }

  // stage 3: softmax over {self, m0..m3}
  const int m0 = (int)__shfl(km, 0, 64);
  const int m1 = (int)__shfl(km, 1, 64);
  const int m2 = (int)__shfl(km, 2, 64);
  const int m3 = (int)__shfl(km, 3, 64);
  const int g = l >> 3, gl = l & 7;
  float dq = 0.f;
  if (g < 5) {
    int msel = (g == 0) ? m0 : (g == 1) ? m1 : (g == 2) ? m2 : m3;
    const float* qrow = base + gl*8;
    const float* kr = (g < 4) ? (kstore + ((size_t)h*MM + msel)*64 + gl*8)
                              : (base + CC + gl*8);
    float4 a0 = *(const float4*)(qrow);
    float4 a1 = *(const float4*)(qrow + 4);
    float4 b0 = *(const float4*)(kr);
    float4 b1 = *(const float4*)(kr + 4);
    dq = a0.x*b0.x + a0.y*b0.y + a0.z*b0.z + a0.w*b0.w
       + a1.x*b1.x + a1.y*b1.y + a1.z*b1.z + a1.w*b1.w;
  }
  dq += __shfl_xor(dq, 1, 64);
  dq += __shfl_xor(dq, 2, 64);
  dq += __shfl_xor(dq, 4, 64);
  float d0 = __shfl(dq,  0, 64)*0.125f;
  float d1 = __shfl(dq,  8, 64)*0.125f;
  float d2 = __shfl(dq, 16, 64)*0.125f;
  float d3 = __shfl(dq, 24, 64)*0.125f;
  float d4 = __shfl(dq, 32, 64)*0.125f;
  float mx = fmaxf(fmaxf(fmaxf(d0,d1),fmaxf(d2,d3)),d4);
  float w0 = __expf(d0-mx), w1 = __expf(d1-mx), w2 = __expf(d2-mx),
        w3 = __expf(d3-mx), w4 = __expf(d4-mx);
  float Z = w0+w1+w2+w3+w4;
  float vv = w4*vh
           + w0*vstore[((size_t)h*MM+m0)*64 + l]
           + w1*vstore[((size_t)h*MM+m1)*64 + l]
           + w2*vstore[((size_t)h*MM+m2)*64 + l]
           + w3*vstore[((size_t)h*MM+m3)*64 + l];
  outp[l] = 0.5f*(vv/Z) + 0.5f*vh;
}

// ---------------- bf16 MFMA causal flash attention (paired, balanced 33 tiles/block) ----------------
__global__ __launch_bounds__(256) void attn_mfma_k(
    const float* __restrict__ qkv, const __hip_bfloat16* __restrict__ kb,
    const __hip_bfloat16* __restrict__ vbT, __hip_bfloat16* __restrict__ yb)
{
  __shared__ __align__(16) char lds[40960];
  const int h = blockIdx.y, bx = blockIdx.x, tid = threadIdx.x;
  const int w = tid>>6, l = tid&63, fr = l&15, fo = l>>4;
  const int wslot = w << 6;
  const __hip_bfloat16* kbh = kb + (size_t)h*TT*64;
  const __hip_bfloat16* vbh = vbT + (size_t)h*64*TT;
  char* Pt = lds + 32768 + w*2048;

  int srow[2], schg[2];
#pragma unroll
  for (int r = 0; r < 2; ++r) {
    int s = r*256 + tid;
    srow[r] = s >> 3;
    schg[r] = (s & 7) ^ ((s >> 3) & 7);
  }

  auto stageKV = [&](int buf, int kt) {
#pragma unroll
    for (int r = 0; r < 2; ++r) {
      gload16(kbh + (size_t)(kt*64 + srow[r])*64 + schg[r]*8,
              lds + buf*16384 + (r*256 + wslot)*16);
      gload16(vbh + (size_t)srow[r]*TT + kt*64 + schg[r]*8,
              lds + buf*16384 + 8192 + (r*256 + wslot)*16);
    }
  };

  for (int half = 0; half < 2; ++half) {
    const int qblk = half ? (31 - bx) : bx;
    const int q0 = qblk * 64;
    bf16x8 qa[2];
    {
      const float* qrow = qkv + (size_t)(q0 + w*16 + fr)*C3 + h*64;
#pragma unroll
      for (int kk = 0; kk < 2; ++kk) {
        float4 u0 = *(const float4*)(qrow + kk*32 + fo*8);
        float4 u1 = *(const float4*)(qrow + kk*32 + fo*8 + 4);
        bf16x8 t;
        t[0]=(__bf16)u0.x; t[1]=(__bf16)u0.y; t[2]=(__bf16)u0.z; t[3]=(__bf16)u0.w;
        t[4]=(__bf16)u1.x; t[5]=(__bf16)u1.y; t[6]=(__bf16)u1.z; t[7]=(__bf16)u1.w;
        qa[kk] = t;
      }
    }
    float mrow[4], lsum[4];
    f32x4 oacc[4];
#pragma unroll
    for (int e = 0; e < 4; ++e) { mrow[e] = -INFINITY; lsum[e] = 0.f; }
#pragma unroll
    for (int jv = 0; jv < 4; ++jv) oacc[jv] = f32x4{0.f,0.f,0.f,0.f};

    const int ntiles = qblk + 1;
    stageKV(0, 0);
    __syncthreads();

    for (int kt = 0; kt < ntiles; ++kt) {
      const int buf = kt & 1;
      if (kt + 1 < ntiles) stageKV(buf ^ 1, kt + 1);
      char* Kt = lds + buf*16384;
      char* Vt = Kt + 8192;

      f32x4 sv[4];
#pragma unroll
      for (int j = 0; j < 4; ++j) {
        int row = j*16 + fr;
        bf16x8 k0f = *(const bf16x8*)(Kt + row*128 + ((fo     ^ (row&7))*16));
        bf16x8 k1f = *(const bf16x8*)(Kt + row*128 + (((4+fo) ^ (row&7))*16));
        f32x4 z = {0.f,0.f,0.f,0.f};
        z = __builtin_amdgcn_mfma_f32_16x16x32_bf16(qa[0], k0f, z, 0,0,0);
        z = __builtin_amdgcn_mfma_f32_16x16x32_bf16(qa[1], k1f, z, 0,0,0);
        sv[j] = z;
      }
      if (kt == qblk) {
#pragma unroll
        for (int j = 0; j < 4; ++j)
#pragma unroll
          for (int e = 0; e < 4; ++e)
            sv[j][e] = (j*16 + fr <= w*16 + fo*4 + e) ? sv[j][e]*0.125f : -INFINITY;
      } else {
#pragma unroll
        for (int j = 0; j < 4; ++j)
#pragma unroll
          for (int e = 0; e < 4; ++e) sv[j][e] *= 0.125f;
      }
      float rmax[4];
#pragma unroll
      for (int e = 0; e < 4; ++e)
        rmax[e] = fmaxf(fmaxf(sv[0][e], sv[1][e]), fmaxf(sv[2][e], sv[3][e]));
#pragma unroll
      for (int off = 1; off < 16; off <<= 1)
#pragma unroll
        for (int e = 0; e < 4; ++e) rmax[e] = fmaxf(rmax[e], __shfl_xor(rmax[e], off, 64));
      float scl[4];
#pragma unroll
      for (int e = 0; e < 4; ++e) {
        float mn = fmaxf(mrow[e], rmax[e]);
        scl[e] = __expf(mrow[e] - mn);
        mrow[e] = mn;
      }
      float rsum[4] = {0.f,0.f,0.f,0.f};
#pragma unroll
      for (int j = 0; j < 4; ++j) {
        int chunkbase = j*2 + (fr>>3);
        int kvoff = (fr&7)*2;
#pragma unroll
        for (int e = 0; e < 4; ++e) {
          float p = __expf(sv[j][e] - mrow[e]);
          rsum[e] += p;
          int qloc = fo*4 + e;
          *(__bf16*)(Pt + qloc*128 + ((chunkbase ^ (qloc&7))*16) + kvoff) = (__bf16)p;
        }
      }
#pragma unroll
      for (int off = 1; off < 16; off <<= 1)
#pragma unroll
        for (int e = 0; e < 4; ++e) rsum[e] += __shfl_xor(rsum[e], off, 64);
#pragma unroll
      for (int e = 0; e < 4; ++e) lsum[e] = lsum[e]*scl[e] + rsum[e];
#pragma unroll
      for (int jv = 0; jv < 4; ++jv)
#pragma unroll
        for (int e = 0; e < 4; ++e) oacc[jv][e] *= scl[e];

      bf16x8 pa0 = *(const bf16x8*)(Pt + fr*128 + ((fo     ^ (fr&7))*16));
      bf16x8 pa1 = *(const bf16x8*)(Pt + fr*128 + (((4+fo) ^ (fr&7))*16));
#pragma unroll
      for (int jv = 0; jv < 4; ++jv) {
        int row = jv*16 + fr;
        bf16x8 v0f = *(const bf16x8*)(Vt + row*128 + ((fo     ^ (row&7))*16));
        bf16x8 v1f = *(const bf16x8*)(Vt + row*128 + (((4+fo) ^ (row&7))*16));
        oacc[jv] = __builtin_amdgcn_mfma_f32_16x16x32_bf16(pa0, v0f, oacc[jv], 0,0,0);
        oacc[jv] = __builtin_amdgcn_mfma_f32_16x16x32_bf16(pa1, v1f, oacc[jv], 0,0,0);
      }
      __syncthreads();
    }
#pragma unroll
    for (int jv = 0; jv < 4; ++jv)
#pragma unroll
      for (int e = 0; e < 4; ++e) {
        int t = q0 + w*16 + fo*4 + e;
        yb[(size_t)t*CC + h*64 + jv*16 + fr] = __float2bfloat16(oacc[jv][e] / lsum[e]);
      }
  }
}

extern "C" void kernel_launch(void* const* d_in, const int* in_sizes, int n_in,
                              void* d_out, int out_size, void* d_ws, size_t ws_size,
                              hipStream_t stream) {
  const float* x   = (const float*)d_in[0];
  const float* wat = (const float*)d_in[1];
  const float* wpr = (const float*)d_in[2];
  const float* kst = (const float*)d_in[3];
  const float* vst = (const float*)d_in[4];
  float* out = (float*)d_out;

  float* ws    = (float*)d_ws;
  float* qkv   = ws;                                   // 6291456
  float* ksn   = qkv + (size_t)6291456;                // 131072
  float* ksnb  = ksn + 131072;                         // 131072
  int*   idxb  = (int*)(ksnb + 131072);                // 131072 (reserved)
  int*   maskb = idxb + 131072;                        // 32768
  __hip_bfloat16* kb = (__hip_bfloat16*)(maskb + 32768);       // 1048576 fs
  float* candRegion = (float*)kb + 1048576;            // 2097152 fs (cand u32 / vnew f32)
  unsigned int* candb = (unsigned int*)candRegion;
  float* vnew = candRegion;
  __hip_bfloat16* vbT = (__hip_bfloat16*)(candRegion + 2097152); // 1048576 fs
  float* split = candRegion + 2097152 + 1048576;       // 5242880 fs region
  __hip_bfloat16* xhi = (__hip_bfloat16*)split;
  __hip_bfloat16* xlo = xhi + 2097152;
  __hip_bfloat16* whi = xlo + 2097152;
  __hip_bfloat16* wlo = whi + 3145728;
  __hip_bfloat16* ksb  = (__hip_bfloat16*)split;       // alias (after qkv GEMM)
  __hip_bfloat16* wprb = ksb + 8388608;
  __hip_bfloat16* yb   = (__hip_bfloat16*)split;       // alias (after chunkmin)

  // 1. conversions: x and wat hi/lo splits (one launch)
  mega1_k<<<dim3(2560), 256, 0, stream>>>(x, xhi, xlo, wat, whi, wlo);
  // 2. qkv = x @ c_attn_w^T (fp32-fidelity split MFMA)
  gemm_mfma_k<true><<<dim3(16*24), 256, 0, stream>>>(xhi, xlo, whi, wlo, qkv, TT, C3, CC);
  // 3. mask + key_store conv + k->bf16 + wpr->bf16 (one launch)
  mega2_k<<<dim3(3600), 256, 0, stream>>>(qkv, maskb, kst, ksb, ksn, ksnb, kb, wpr, wprb);
  // 4. phase A: MFMA chunk-min scoring
  knn_chunkmin_k<<<dim3(1024), 256, 0, stream>>>(kb, ksb, ksnb, candb);
  // 5. phase B fused: rescore -> top-4 -> v_new
  knn_fused_k<<<dim3(HH*TT/4), 256, 0, stream>>>(candb, qkv, kst, vst, ksn, maskb, vnew);
  // 6. v_new -> transposed bf16
  vtrans_k<<<dim3(32, HH), 256, 0, stream>>>(vnew, vbT);
  // 7. causal flash attention (paired/balanced)
  attn_mfma_k<<<dim3(16, HH), 256, 0, stream>>>(qkv, kb, vbT, yb);
  // 8. out = y @ c_proj_w^T
  gemm_mfma_k<false><<<dim3(16*8), 256, 0, stream>>>(yb, nullptr, wprb, nullptr, out, TT, CC, CC);
}